// Round 7
// baseline (315.781 us; speedup 1.0000x reference)
//
#include <hip/hip_runtime.h>
#include <hip/hip_bf16.h>

#define NHEAD 4
#define NEG 0.2f

typedef __bf16 bf16x8 __attribute__((ext_vector_type(8)));
typedef float f32x4 __attribute__((ext_vector_type(4)));

__device__ __forceinline__ float blo(unsigned u) { return __uint_as_float(u << 16); }
__device__ __forceinline__ float bhi(unsigned u) { return __uint_as_float(u & 0xffff0000u); }
__device__ __forceinline__ unsigned short fbits(float f) {
    __bf16 h = (__bf16)f;
    return *(unsigned short*)&h;
}

// ---------------- CSR build ----------------

__global__ __launch_bounds__(256) void hist_k(const int* __restrict__ dst,
                                              int* __restrict__ deg, int E) {
    int e = blockIdx.x * 256 + threadIdx.x;
    if (e < E) atomicAdd(&deg[dst[e]], 1);
}

__global__ __launch_bounds__(256) void partial_k(const int* __restrict__ deg,
                                                 int* __restrict__ bsum, int n) {
    int t = threadIdx.x;
    int base = blockIdx.x * 2048 + t * 8;
    int s = 0;
#pragma unroll
    for (int i = 0; i < 8; ++i) {
        int idx = base + i;
        if (idx < n) s += deg[idx];
    }
#pragma unroll
    for (int off = 32; off; off >>= 1) s += __shfl_down(s, off, 64);
    __shared__ int ws[4];
    if ((t & 63) == 0) ws[t >> 6] = s;
    __syncthreads();
    if (t == 0) bsum[blockIdx.x] = ws[0] + ws[1] + ws[2] + ws[3];
}

__global__ __launch_bounds__(256) void bscan_k(const int* __restrict__ bsum,
                                               int* __restrict__ boff, int nb) {
    __shared__ int sh[256];
    int t = threadIdx.x;
    int v = (t < nb) ? bsum[t] : 0;
    sh[t] = v;
    __syncthreads();
    for (int off = 1; off < 256; off <<= 1) {
        int u = (t >= off) ? sh[t - off] : 0;
        __syncthreads();
        sh[t] += u;
        __syncthreads();
    }
    if (t < nb) boff[t] = sh[t] - v;  // exclusive
}

__global__ __launch_bounds__(256) void rescan_k(const int* __restrict__ deg,
                                                const int* __restrict__ boff,
                                                int* __restrict__ rowptr,
                                                int* __restrict__ fill,
                                                int n, int total) {
    __shared__ int ts[256];
    int t = threadIdx.x;
    int base = blockIdx.x * 2048 + t * 8;
    int v[8];
    int s = 0;
#pragma unroll
    for (int i = 0; i < 8; ++i) {
        int idx = base + i;
        v[i] = (idx < n) ? deg[idx] : 0;
        s += v[i];
    }
    ts[t] = s;
    __syncthreads();
    for (int off = 1; off < 256; off <<= 1) {
        int u = (t >= off) ? ts[t - off] : 0;
        __syncthreads();
        ts[t] += u;
        __syncthreads();
    }
    int run = boff[blockIdx.x] + ts[t] - s;
#pragma unroll
    for (int i = 0; i < 8; ++i) {
        int idx = base + i;
        if (idx < n) {
            rowptr[idx] = run;
            fill[idx] = run;
            run += v[i];
        }
    }
    if (blockIdx.x == 0 && t == 0) rowptr[n] = total;
}

__global__ __launch_bounds__(256) void scatter_k(const int* __restrict__ src,
                                                 const int* __restrict__ dst,
                                                 const float* __restrict__ ew,
                                                 int* __restrict__ fill,
                                                 int* __restrict__ srcs,
                                                 float* __restrict__ wsrt, int E) {
    int e = blockIdx.x * 256 + threadIdx.x;
    if (e < E) {
        int d = dst[e];
        int p = atomicAdd(&fill[d], 1);
        srcs[p] = src[e];
        wsrt[p] = ew[e];
    }
}

// ---------------- prep: v_h = W_h . att_h, c_h = b_h . att_h (all 3 layers) ----------------

__global__ __launch_bounds__(256) void prep_k(const float* __restrict__ W1, const float* __restrict__ att1, const float* __restrict__ b1,
                                              const float* __restrict__ W2, const float* __restrict__ att2, const float* __restrict__ b2,
                                              const float* __restrict__ W3, const float* __restrict__ att3, const float* __restrict__ b3,
                                              float* __restrict__ v1, float* __restrict__ v2, float* __restrict__ v3,
                                              float* __restrict__ c1, float* __restrict__ c2, float* __restrict__ c3) {
    int tid = blockIdx.x * 256 + threadIdx.x;
    if (tid < 512) {
        int h = tid >> 7, k = tid & 127;
        float p = 0.f;
        for (int d = 0; d < 64; ++d) p += W1[k * 256 + h * 64 + d] * att1[h * 64 + d];
        v1[h * 128 + k] = p;
    } else if (tid < 768) {
        int t = tid - 512, h = t >> 6, k = t & 63;
        float p = 0.f;
        for (int d = 0; d < 64; ++d) p += W2[k * 256 + h * 64 + d] * att2[h * 64 + d];
        v2[h * 64 + k] = p;
    } else if (tid < 1024) {
        int t = tid - 768, h = t >> 6, k = t & 63;
        float p = 0.f;
        for (int d = 0; d < 128; ++d) p += W3[k * 512 + h * 128 + d] * att3[h * 128 + d];
        v3[h * 64 + k] = p;
    } else if (tid < 1028) {
        int h = tid - 1024;
        float p = 0.f;
        for (int d = 0; d < 64; ++d) p += b1[h * 64 + d] * att1[h * 64 + d];
        c1[h] = p;
    } else if (tid < 1032) {
        int h = tid - 1028;
        float p = 0.f;
        for (int d = 0; d < 64; ++d) p += b2[h * 64 + d] * att2[h * 64 + d];
        c2[h] = p;
    } else if (tid < 1036) {
        int h = tid - 1032;
        float p = 0.f;
        for (int d = 0; d < 128; ++d) p += b3[h * 128 + d] * att3[h * 128 + d];
        c3[h] = p;
    }
}

// ---------------- stacked W packs: Ws[d][h*K+k] = W[k][h*D+d], bf16 ----------------

__global__ __launch_bounds__(256) void wpack3_k(const float* __restrict__ W1,
                                                const float* __restrict__ W2,
                                                const float* __restrict__ W3,
                                                unsigned short* __restrict__ Ws1,
                                                unsigned short* __restrict__ Ws2,
                                                unsigned short* __restrict__ Ws3) {
    int tid = blockIdx.x * 256 + threadIdx.x;
    if (tid < 32768) {  // L1: d<64, h<4, k<128 ; Ws1[d*512 + h*128 + k]
        int d = tid >> 9, r = tid & 511, h = r >> 7, k = r & 127;
        Ws1[tid] = fbits(W1[k * 256 + h * 64 + d]);
    } else if (tid < 49152) {  // L2: d<64, h<4, k<64 ; Ws2[d*256 + h*64 + k]
        int t = tid - 32768;
        int d = t >> 8, r = t & 255, h = r >> 6, k = r & 63;
        Ws2[t] = fbits(W2[k * 256 + h * 64 + d]);
    } else if (tid < 81920) {  // L3: d<128, h<4, k<64 ; Ws3[d*256 + h*64 + k]
        int t = tid - 49152;
        int d = t >> 8, r = t & 255, h = r >> 6, k = r & 63;
        Ws3[t] = fbits(W3[k * 512 + h * 128 + d]);
    }
}

// ---------------- x pack to bf16 + layer-1 scores ----------------

__global__ __launch_bounds__(256) void xpack_score_k(const float* __restrict__ x,
                                                     const float* __restrict__ v1,
                                                     const float* __restrict__ c1,
                                                     unsigned* __restrict__ xb,
                                                     float* __restrict__ s, int n) {
    int gt = blockIdx.x * 256 + threadIdx.x;
    int node = gt >> 6, lane = gt & 63;
    if (node >= n) return;
    float2 xv = ((const float2*)(x + (size_t)node * 128))[lane];
    xb[(size_t)node * 64 + lane] = (unsigned)fbits(xv.x) | ((unsigned)fbits(xv.y) << 16);
    int d0 = 2 * lane;
    float p0 = xv.x * v1[0 * 128 + d0] + xv.y * v1[0 * 128 + d0 + 1];
    float p1 = xv.x * v1[1 * 128 + d0] + xv.y * v1[1 * 128 + d0 + 1];
    float p2 = xv.x * v1[2 * 128 + d0] + xv.y * v1[2 * 128 + d0 + 1];
    float p3 = xv.x * v1[3 * 128 + d0] + xv.y * v1[3 * 128 + d0 + 1];
#pragma unroll
    for (int off = 32; off; off >>= 1) {
        p0 += __shfl_xor(p0, off, 64);
        p1 += __shfl_xor(p1, off, 64);
        p2 += __shfl_xor(p2, off, 64);
        p3 += __shfl_xor(p3, off, 64);
    }
    if (lane == 0)
        *(float4*)&s[(size_t)node * 4] = make_float4(p0 + c1[0], p1 + c1[1], p2 + c1[2], p3 + c1[3]);
}

// ---------------- per-edge alpha ----------------

__global__ __launch_bounds__(256) void alpha_k(const int* __restrict__ srcs,
                                               const float* __restrict__ wsrt,
                                               const float* __restrict__ s,
                                               float* __restrict__ alpha, int E) {
    int e = blockIdx.x * 256 + threadIdx.x;
    if (e >= E) return;
    int sn = srcs[e];
    float w = wsrt[e];
    float4 sv = *(const float4*)&s[(size_t)sn * NHEAD];
    float a0 = (sv.x > 0.f ? sv.x : NEG * sv.x) * w;
    float a1 = (sv.y > 0.f ? sv.y : NEG * sv.y) * w;
    float a2 = (sv.z > 0.f ? sv.z : NEG * sv.z) * w;
    float a3 = (sv.w > 0.f ? sv.w : NEG * sv.w) * w;
    float m = fmaxf(fmaxf(a0, a1), fmaxf(a2, a3));
    float e0 = __expf(a0 - m), e1 = __expf(a1 - m);
    float e2 = __expf(a2 - m), e3 = __expf(a3 - m);
    float inv = 0.25f / (e0 + e1 + e2 + e3);  // fold mean-over-heads
    *(float4*)&alpha[(size_t)e * 4] = make_float4(e0 * inv, e1 * inv, e2 * inv, e3 * inv);
}

// ---------------- linear aggregation (half-wave per node) ----------------

template <int K>
__global__ __launch_bounds__(256) void aggr_lin_k(const int* __restrict__ rowptr,
                                                  const int* __restrict__ srcs,
                                                  const float* __restrict__ alpha,
                                                  const unsigned* __restrict__ xb,
                                                  float* __restrict__ g,
                                                  float* __restrict__ A, int n) {
    int gt = blockIdx.x * 256 + threadIdx.x;
    int node = gt >> 5, lid = gt & 31;
    if (node >= n) return;
    int beg = rowptr[node], end = rowptr[node + 1];
    constexpr int DW = K / 64;  // uints per lane (1 or 2)

    float acc[4][2 * DW];
#pragma unroll
    for (int h = 0; h < 4; ++h)
#pragma unroll
        for (int j = 0; j < 2 * DW; ++j) acc[h][j] = 0.f;
    float aA0 = 0.f, aA1 = 0.f, aA2 = 0.f, aA3 = 0.f;

    auto accum = [&](float4 al, const unsigned* u) {
#pragma unroll
        for (int j = 0; j < DW; ++j) {
            float x0 = blo(u[j]), x1 = bhi(u[j]);
            acc[0][2 * j] += al.x * x0; acc[0][2 * j + 1] += al.x * x1;
            acc[1][2 * j] += al.y * x0; acc[1][2 * j + 1] += al.y * x1;
            acc[2][2 * j] += al.z * x0; acc[2][2 * j + 1] += al.z * x1;
            acc[3][2 * j] += al.w * x0; acc[3][2 * j + 1] += al.w * x1;
        }
        aA0 += al.x; aA1 += al.y; aA2 += al.z; aA3 += al.w;
    };

    int e = beg;
    for (; e + 1 < end; e += 2) {
        int snA = srcs[e], snB = srcs[e + 1];
        float4 alA = *(const float4*)&alpha[(size_t)e * 4];
        float4 alB = *(const float4*)&alpha[(size_t)(e + 1) * 4];
        unsigned uA[DW], uB[DW];
        if constexpr (DW == 1) {
            uA[0] = xb[(size_t)snA * 32 + lid];
            uB[0] = xb[(size_t)snB * 32 + lid];
        } else {
            uint2 ta = ((const uint2*)xb)[(size_t)snA * 32 + lid];
            uint2 tb = ((const uint2*)xb)[(size_t)snB * 32 + lid];
            uA[0] = ta.x; uA[1] = ta.y;
            uB[0] = tb.x; uB[1] = tb.y;
        }
        accum(alA, uA);
        accum(alB, uB);
    }
    if (e < end) {
        int sn = srcs[e];
        float4 al = *(const float4*)&alpha[(size_t)e * 4];
        unsigned u[DW];
        if constexpr (DW == 1) {
            u[0] = xb[(size_t)sn * 32 + lid];
        } else {
            uint2 t = ((const uint2*)xb)[(size_t)sn * 32 + lid];
            u[0] = t.x; u[1] = t.y;
        }
        accum(al, u);
    }

    size_t gb = (size_t)node * (4 * K);
#pragma unroll
    for (int h = 0; h < 4; ++h) {
        if constexpr (DW == 1)
            *(float2*)&g[gb + h * K + 2 * lid] = make_float2(acc[h][0], acc[h][1]);
        else
            *(float4*)&g[gb + h * K + 4 * lid] =
                make_float4(acc[h][0], acc[h][1], acc[h][2], acc[h][3]);
    }
    if (lid == 0) *(float4*)&A[(size_t)node * 4] = make_float4(aA0, aA1, aA2, aA3);
}

// ---------------- post-GEMM, K-split across 4 waves + LDS reduce ----------------
// Block = one 16-row strip. Wave w computes ks in [w*KW, (w+1)*KW); partials
// reduced in LDS; wave 0 does bias-via-A, ReLU, store, fused next-layer score.

template <int HK, int D, bool LAST>
__global__ __launch_bounds__(256) void gemm_post_k(const float* __restrict__ g,
                                                   const unsigned short* __restrict__ Ws,
                                                   const float* __restrict__ bias,
                                                   const float* __restrict__ A,
                                                   const float* __restrict__ vnext,
                                                   const float* __restrict__ cnext,
                                                   unsigned short* __restrict__ aout,
                                                   float* __restrict__ fout,
                                                   float* __restrict__ snext,
                                                   int nrows) {
    constexpr int KS = HK / 32;
    constexpr int KW = KS / 4;   // ks steps per wave
    constexpr int NC = D / 16;
    int wid = threadIdx.x >> 6, lane = threadIdx.x & 63;
    int r0 = blockIdx.x * 16;
    if (r0 >= nrows) return;
    int lrow = lane & 15, gq = lane >> 4, lk = gq * 8;

    __shared__ f32x4 red[NC * 4 * 64];

    // A fragments for this wave's K slice, split hi/lo
    bf16x8 ah[KW], al[KW];
    const float* gp = g + (size_t)(r0 + lrow) * HK + (size_t)wid * KW * 32 + lk;
#pragma unroll
    for (int ks = 0; ks < KW; ++ks) {
        f32x4 f0 = *(const f32x4*)(gp + ks * 32);
        f32x4 f1 = *(const f32x4*)(gp + ks * 32 + 4);
#pragma unroll
        for (int j = 0; j < 4; ++j) {
            __bf16 h0 = (__bf16)f0[j];
            __bf16 h1 = (__bf16)f1[j];
            ah[ks][j] = h0;
            ah[ks][4 + j] = h1;
            al[ks][j] = (__bf16)(f0[j] - (float)h0);
            al[ks][4 + j] = (__bf16)(f1[j] - (float)h1);
        }
    }

    f32x4 acc[NC];
#pragma unroll
    for (int c = 0; c < NC; ++c)
#pragma unroll
        for (int r = 0; r < 4; ++r) acc[c][r] = 0.f;

    const __bf16* wsp = (const __bf16*)Ws;
#pragma unroll
    for (int ks = 0; ks < KW; ++ks) {
#pragma unroll
        for (int c = 0; c < NC; ++c) {
            bf16x8 bfr = *(const bf16x8*)(wsp + (size_t)(c * 16 + lrow) * HK +
                                          (size_t)(wid * KW + ks) * 32 + lk);
            acc[c] = __builtin_amdgcn_mfma_f32_16x16x32_bf16(ah[ks], bfr, acc[c], 0, 0, 0);
            acc[c] = __builtin_amdgcn_mfma_f32_16x16x32_bf16(al[ks], bfr, acc[c], 0, 0, 0);
        }
    }

#pragma unroll
    for (int c = 0; c < NC; ++c) red[(c * 4 + wid) * 64 + lane] = acc[c];
    __syncthreads();
    if (wid != 0) return;

    // ---- wave 0: reduce partials + epilogue ----
    float4 Ar[4];
#pragma unroll
    for (int r = 0; r < 4; ++r) Ar[r] = *(const float4*)&A[(size_t)(r0 + gq * 4 + r) * 4];

    float sc[4][4];
#pragma unroll
    for (int h = 0; h < 4; ++h)
#pragma unroll
        for (int r = 0; r < 4; ++r) sc[h][r] = 0.f;

#pragma unroll
    for (int c = 0; c < NC; ++c) {
        f32x4 sum = red[(c * 4 + 0) * 64 + lane];
#pragma unroll
        for (int w = 1; w < 4; ++w) {
            f32x4 p = red[(c * 4 + w) * 64 + lane];
#pragma unroll
            for (int r = 0; r < 4; ++r) sum[r] += p[r];
        }

        int col = c * 16 + lrow;
        float bb0 = bias[0 * D + col], bb1 = bias[1 * D + col];
        float bb2 = bias[2 * D + col], bb3 = bias[3 * D + col];
        float vv0 = 0.f, vv1 = 0.f, vv2 = 0.f, vv3 = 0.f;
        if constexpr (!LAST) {
            vv0 = vnext[0 * D + col]; vv1 = vnext[1 * D + col];
            vv2 = vnext[2 * D + col]; vv3 = vnext[3 * D + col];
        }
#pragma unroll
        for (int r = 0; r < 4; ++r) {
            float val = sum[r] + Ar[r].x * bb0 + Ar[r].y * bb1 + Ar[r].z * bb2 + Ar[r].w * bb3;
            int row = r0 + gq * 4 + r;
            if constexpr (LAST) {
                if (row < nrows) fout[(size_t)row * D + col] = val;
            } else {
                val = fmaxf(val, 0.f);
                if (row < nrows) aout[(size_t)row * D + col] = fbits(val);
                sc[0][r] += val * vv0;
                sc[1][r] += val * vv1;
                sc[2][r] += val * vv2;
                sc[3][r] += val * vv3;
            }
        }
    }

    if constexpr (!LAST) {
#pragma unroll
        for (int m = 1; m < 16; m <<= 1) {
#pragma unroll
            for (int h = 0; h < 4; ++h)
#pragma unroll
                for (int r = 0; r < 4; ++r) sc[h][r] += __shfl_xor(sc[h][r], m, 64);
        }
#pragma unroll
        for (int r = 0; r < 4; ++r) {
            if (lrow == r) {
                int row = r0 + gq * 4 + r;
                if (row < nrows)
                    *(float4*)&snext[(size_t)row * 4] =
                        make_float4(sc[0][r] + cnext[0], sc[1][r] + cnext[1],
                                    sc[2][r] + cnext[2], sc[3][r] + cnext[3]);
            }
        }
    }
}

// ---------------- launch ----------------

extern "C" void kernel_launch(void* const* d_in, const int* in_sizes, int n_in,
                              void* d_out, int out_size, void* d_ws, size_t ws_size,
                              hipStream_t stream) {
    const float* x    = (const float*)d_in[0];
    const int*   ei   = (const int*)d_in[1];
    const float* ew   = (const float*)d_in[2];
    const float* W1   = (const float*)d_in[3];
    const float* b1   = (const float*)d_in[4];
    const float* att1 = (const float*)d_in[5];
    const float* W2   = (const float*)d_in[6];
    const float* b2   = (const float*)d_in[7];
    const float* att2 = (const float*)d_in[8];
    const float* W3   = (const float*)d_in[9];
    const float* b3   = (const float*)d_in[10];
    const float* att3 = (const float*)d_in[11];

    const int N = in_sizes[0] / 128;
    const int E = in_sizes[2];
    const int* src = ei;
    const int* dst = ei + E;

    char* wp = (char*)d_ws;
    auto alloc = [&](size_t bytes) -> void* {
        void* p = (void*)wp;
        wp += (bytes + 511) & ~(size_t)511;
        return p;
    };
    int*   deg    = (int*)alloc((size_t)N * 4);
    int*   rowptr = (int*)alloc((size_t)(N + 1) * 4);
    int*   fill   = (int*)alloc((size_t)N * 4);
    int*   bsum   = (int*)alloc(256 * 4);
    int*   boff   = (int*)alloc(256 * 4);
    int*   srcs   = (int*)alloc((size_t)E * 4);
    float* wsrt   = (float*)alloc((size_t)E * 4);
    unsigned* xb  = (unsigned*)alloc((size_t)N * 64 * 4);     // x bf16 [N,128]
    float* s      = (float*)alloc((size_t)N * 4 * 4);
    float* alpha  = (float*)alloc((size_t)E * 4 * 4);
    float* A      = (float*)alloc((size_t)N * 4 * 4);
    float* g      = (float*)alloc((size_t)N * 512 * 4);       // [N, H*K] f32, max H*128
    unsigned short* a1 = (unsigned short*)alloc((size_t)N * 64 * 2);
    unsigned short* a2 = (unsigned short*)alloc((size_t)N * 64 * 2);
    float* v1 = (float*)alloc(512 * 4);
    float* v2 = (float*)alloc(256 * 4);
    float* v3 = (float*)alloc(256 * 4);
    float* c1 = (float*)alloc(16);
    float* c2 = (float*)alloc(16);
    float* c3 = (float*)alloc(16);
    unsigned short* Ws1 = (unsigned short*)alloc(32768 * 2);
    unsigned short* Ws2 = (unsigned short*)alloc(16384 * 2);
    unsigned short* Ws3 = (unsigned short*)alloc(32768 * 2);

    // --- prep (independent of CSR) ---
    wpack3_k<<<320, 256, 0, stream>>>(W1, W2, W3, Ws1, Ws2, Ws3);
    prep_k<<<5, 256, 0, stream>>>(W1, att1, b1, W2, att2, b2, W3, att3, b3,
                                  v1, v2, v3, c1, c2, c3);
    int gx = (N * 64 + 255) / 256;
    xpack_score_k<<<gx, 256, 0, stream>>>(x, v1, c1, xb, s, N);

    // --- CSR build (shared by all 3 layers) ---
    hipMemsetAsync(deg, 0, (size_t)N * 4, stream);
    int ge = (E + 255) / 256;
    int nb = (N + 2047) / 2048;
    hist_k<<<ge, 256, 0, stream>>>(dst, deg, E);
    partial_k<<<nb, 256, 0, stream>>>(deg, bsum, N);
    bscan_k<<<1, 256, 0, stream>>>(bsum, boff, nb);
    rescan_k<<<nb, 256, 0, stream>>>(deg, boff, rowptr, fill, N, E);
    scatter_k<<<ge, 256, 0, stream>>>(src, dst, ew, fill, srcs, wsrt, E);

    int ga = (N * 32 + 255) / 256;   // half-wave per node
    int gp = (N + 15) / 16;          // post-GEMM: one 16-row strip per BLOCK

    // --- layer 1: gather x (K=128) -> g -> [N,512]@[512,64] ---
    alpha_k<<<ge, 256, 0, stream>>>(srcs, wsrt, s, alpha, E);
    aggr_lin_k<128><<<ga, 256, 0, stream>>>(rowptr, srcs, alpha, xb, g, A, N);
    gemm_post_k<512, 64, false><<<gp, 256, 0, stream>>>(g, Ws1, b1, A, v2, c2,
                                                        a1, nullptr, s, N);

    // --- layer 2: gather a1 (K=64) -> g -> [N,256]@[256,64] ---
    alpha_k<<<ge, 256, 0, stream>>>(srcs, wsrt, s, alpha, E);
    aggr_lin_k<64><<<ga, 256, 0, stream>>>(rowptr, srcs, alpha, (const unsigned*)a1, g, A, N);
    gemm_post_k<256, 64, false><<<gp, 256, 0, stream>>>(g, Ws2, b2, A, v3, c3,
                                                        a2, nullptr, s, N);

    // --- layer 3: gather a2 (K=64) -> g -> [N,256]@[256,128] ---
    alpha_k<<<ge, 256, 0, stream>>>(srcs, wsrt, s, alpha, E);
    aggr_lin_k<64><<<ga, 256, 0, stream>>>(rowptr, srcs, alpha, (const unsigned*)a2, g, A, N);
    gemm_post_k<256, 128, true><<<gp, 256, 0, stream>>>(g, Ws3, b3, A, nullptr, nullptr,
                                                        nullptr, (float*)d_out, nullptr, N);
}

// Round 8
// 253.839 us; speedup vs baseline: 1.2440x; 1.2440x over previous
//
#include <hip/hip_runtime.h>
#include <hip/hip_bf16.h>

#define NHEAD 4
#define NEG 0.2f

typedef __bf16 bf16x8 __attribute__((ext_vector_type(8)));
typedef __bf16 bf16x4 __attribute__((ext_vector_type(4)));
typedef float f32x4 __attribute__((ext_vector_type(4)));

__device__ __forceinline__ float blo(unsigned u) { return __uint_as_float(u << 16); }
__device__ __forceinline__ float bhi(unsigned u) { return __uint_as_float(u & 0xffff0000u); }
__device__ __forceinline__ unsigned short fbits(float f) {
    __bf16 h = (__bf16)f;
    return *(unsigned short*)&h;
}

// ---------------- CSR build ----------------

__global__ __launch_bounds__(256) void hist_k(const int* __restrict__ dst,
                                              int* __restrict__ deg, int E) {
    int e = blockIdx.x * 256 + threadIdx.x;
    if (e < E) atomicAdd(&deg[dst[e]], 1);
}

__global__ __launch_bounds__(256) void partial_k(const int* __restrict__ deg,
                                                 int* __restrict__ bsum, int n) {
    int t = threadIdx.x;
    int base = blockIdx.x * 2048 + t * 8;
    int s = 0;
#pragma unroll
    for (int i = 0; i < 8; ++i) {
        int idx = base + i;
        if (idx < n) s += deg[idx];
    }
#pragma unroll
    for (int off = 32; off; off >>= 1) s += __shfl_down(s, off, 64);
    __shared__ int ws[4];
    if ((t & 63) == 0) ws[t >> 6] = s;
    __syncthreads();
    if (t == 0) bsum[blockIdx.x] = ws[0] + ws[1] + ws[2] + ws[3];
}

__global__ __launch_bounds__(256) void bscan_k(const int* __restrict__ bsum,
                                               int* __restrict__ boff, int nb) {
    __shared__ int sh[256];
    int t = threadIdx.x;
    int v = (t < nb) ? bsum[t] : 0;
    sh[t] = v;
    __syncthreads();
    for (int off = 1; off < 256; off <<= 1) {
        int u = (t >= off) ? sh[t - off] : 0;
        __syncthreads();
        sh[t] += u;
        __syncthreads();
    }
    if (t < nb) boff[t] = sh[t] - v;  // exclusive
}

__global__ __launch_bounds__(256) void rescan_k(const int* __restrict__ deg,
                                                const int* __restrict__ boff,
                                                int* __restrict__ rowptr,
                                                int* __restrict__ fill,
                                                int n, int total) {
    __shared__ int ts[256];
    int t = threadIdx.x;
    int base = blockIdx.x * 2048 + t * 8;
    int v[8];
    int s = 0;
#pragma unroll
    for (int i = 0; i < 8; ++i) {
        int idx = base + i;
        v[i] = (idx < n) ? deg[idx] : 0;
        s += v[i];
    }
    ts[t] = s;
    __syncthreads();
    for (int off = 1; off < 256; off <<= 1) {
        int u = (t >= off) ? ts[t - off] : 0;
        __syncthreads();
        ts[t] += u;
        __syncthreads();
    }
    int run = boff[blockIdx.x] + ts[t] - s;
#pragma unroll
    for (int i = 0; i < 8; ++i) {
        int idx = base + i;
        if (idx < n) {
            rowptr[idx] = run;
            fill[idx] = run;
            run += v[i];
        }
    }
    if (blockIdx.x == 0 && t == 0) rowptr[n] = total;
}

__global__ __launch_bounds__(256) void scatter_k(const int* __restrict__ src,
                                                 const int* __restrict__ dst,
                                                 const float* __restrict__ ew,
                                                 int* __restrict__ fill,
                                                 int* __restrict__ srcs,
                                                 float* __restrict__ wsrt, int E) {
    int e = blockIdx.x * 256 + threadIdx.x;
    if (e < E) {
        int d = dst[e];
        int p = atomicAdd(&fill[d], 1);
        srcs[p] = src[e];
        wsrt[p] = ew[e];
    }
}

// ---------------- prep: v_h = W_h . att_h, c_h = b_h . att_h (all 3 layers) ----------------

__global__ __launch_bounds__(256) void prep_k(const float* __restrict__ W1, const float* __restrict__ att1, const float* __restrict__ b1,
                                              const float* __restrict__ W2, const float* __restrict__ att2, const float* __restrict__ b2,
                                              const float* __restrict__ W3, const float* __restrict__ att3, const float* __restrict__ b3,
                                              float* __restrict__ v1, float* __restrict__ v2, float* __restrict__ v3,
                                              float* __restrict__ c1, float* __restrict__ c2, float* __restrict__ c3) {
    int tid = blockIdx.x * 256 + threadIdx.x;
    if (tid < 512) {
        int h = tid >> 7, k = tid & 127;
        float p = 0.f;
        for (int d = 0; d < 64; ++d) p += W1[k * 256 + h * 64 + d] * att1[h * 64 + d];
        v1[h * 128 + k] = p;
    } else if (tid < 768) {
        int t = tid - 512, h = t >> 6, k = t & 63;
        float p = 0.f;
        for (int d = 0; d < 64; ++d) p += W2[k * 256 + h * 64 + d] * att2[h * 64 + d];
        v2[h * 64 + k] = p;
    } else if (tid < 1024) {
        int t = tid - 768, h = t >> 6, k = t & 63;
        float p = 0.f;
        for (int d = 0; d < 128; ++d) p += W3[k * 512 + h * 128 + d] * att3[h * 128 + d];
        v3[h * 64 + k] = p;
    } else if (tid < 1028) {
        int h = tid - 1024;
        float p = 0.f;
        for (int d = 0; d < 64; ++d) p += b1[h * 64 + d] * att1[h * 64 + d];
        c1[h] = p;
    } else if (tid < 1032) {
        int h = tid - 1028;
        float p = 0.f;
        for (int d = 0; d < 64; ++d) p += b2[h * 64 + d] * att2[h * 64 + d];
        c2[h] = p;
    } else if (tid < 1036) {
        int h = tid - 1032;
        float p = 0.f;
        for (int d = 0; d < 128; ++d) p += b3[h * 128 + d] * att3[h * 128 + d];
        c3[h] = p;
    }
}

// ---------------- stacked W packs: Ws[d][h*K+k] = W[k][h*D+d], bf16 ----------------

__global__ __launch_bounds__(256) void wpack3_k(const float* __restrict__ W1,
                                                const float* __restrict__ W2,
                                                const float* __restrict__ W3,
                                                unsigned short* __restrict__ Ws1,
                                                unsigned short* __restrict__ Ws2,
                                                unsigned short* __restrict__ Ws3) {
    int tid = blockIdx.x * 256 + threadIdx.x;
    if (tid < 32768) {  // L1: d<64, h<4, k<128 ; Ws1[d*512 + h*128 + k]
        int d = tid >> 9, r = tid & 511, h = r >> 7, k = r & 127;
        Ws1[tid] = fbits(W1[k * 256 + h * 64 + d]);
    } else if (tid < 49152) {  // L2: d<64, h<4, k<64 ; Ws2[d*256 + h*64 + k]
        int t = tid - 32768;
        int d = t >> 8, r = t & 255, h = r >> 6, k = r & 63;
        Ws2[t] = fbits(W2[k * 256 + h * 64 + d]);
    } else if (tid < 81920) {  // L3: d<128, h<4, k<64 ; Ws3[d*256 + h*64 + k]
        int t = tid - 49152;
        int d = t >> 8, r = t & 255, h = r >> 6, k = r & 63;
        Ws3[t] = fbits(W3[k * 512 + h * 128 + d]);
    }
}

// ---------------- x pack to bf16 + layer-1 scores ----------------

__global__ __launch_bounds__(256) void xpack_score_k(const float* __restrict__ x,
                                                     const float* __restrict__ v1,
                                                     const float* __restrict__ c1,
                                                     unsigned* __restrict__ xb,
                                                     float* __restrict__ s, int n) {
    int gt = blockIdx.x * 256 + threadIdx.x;
    int node = gt >> 6, lane = gt & 63;
    if (node >= n) return;
    float2 xv = ((const float2*)(x + (size_t)node * 128))[lane];
    xb[(size_t)node * 64 + lane] = (unsigned)fbits(xv.x) | ((unsigned)fbits(xv.y) << 16);
    int d0 = 2 * lane;
    float p0 = xv.x * v1[0 * 128 + d0] + xv.y * v1[0 * 128 + d0 + 1];
    float p1 = xv.x * v1[1 * 128 + d0] + xv.y * v1[1 * 128 + d0 + 1];
    float p2 = xv.x * v1[2 * 128 + d0] + xv.y * v1[2 * 128 + d0 + 1];
    float p3 = xv.x * v1[3 * 128 + d0] + xv.y * v1[3 * 128 + d0 + 1];
#pragma unroll
    for (int off = 32; off; off >>= 1) {
        p0 += __shfl_xor(p0, off, 64);
        p1 += __shfl_xor(p1, off, 64);
        p2 += __shfl_xor(p2, off, 64);
        p3 += __shfl_xor(p3, off, 64);
    }
    if (lane == 0)
        *(float4*)&s[(size_t)node * 4] = make_float4(p0 + c1[0], p1 + c1[1], p2 + c1[2], p3 + c1[3]);
}

// ---------------- per-edge alpha ----------------

__global__ __launch_bounds__(256) void alpha_k(const int* __restrict__ srcs,
                                               const float* __restrict__ wsrt,
                                               const float* __restrict__ s,
                                               float* __restrict__ alpha, int E) {
    int e = blockIdx.x * 256 + threadIdx.x;
    if (e >= E) return;
    int sn = srcs[e];
    float w = wsrt[e];
    float4 sv = *(const float4*)&s[(size_t)sn * NHEAD];
    float a0 = (sv.x > 0.f ? sv.x : NEG * sv.x) * w;
    float a1 = (sv.y > 0.f ? sv.y : NEG * sv.y) * w;
    float a2 = (sv.z > 0.f ? sv.z : NEG * sv.z) * w;
    float a3 = (sv.w > 0.f ? sv.w : NEG * sv.w) * w;
    float m = fmaxf(fmaxf(a0, a1), fmaxf(a2, a3));
    float e0 = __expf(a0 - m), e1 = __expf(a1 - m);
    float e2 = __expf(a2 - m), e3 = __expf(a3 - m);
    float inv = 0.25f / (e0 + e1 + e2 + e3);  // fold mean-over-heads
    *(float4*)&alpha[(size_t)e * 4] = make_float4(e0 * inv, e1 * inv, e2 * inv, e3 * inv);
}

// ---------------- fused layer: gather -> LDS (split bf16) -> MFMA -> epilogue ----------------
// Block = 16 nodes. Gather: 16 lanes/node, f32 accumulate per head.
// MFMA: D-split across 4 waves; A-frags from LDS, B from packed Ws (L2).
// Epilogue: bias-via-A, ReLU, store bf16 (or f32 for LAST), fused next-layer score.

template <int K, int D, bool LAST>
__global__ __launch_bounds__(256) void fused_k(const int* __restrict__ rowptr,
                                               const int* __restrict__ srcs,
                                               const float* __restrict__ alpha,
                                               const unsigned* __restrict__ xb,
                                               const unsigned short* __restrict__ Ws,
                                               const float* __restrict__ bias,
                                               const float* __restrict__ vnext,
                                               const float* __restrict__ cnext,
                                               unsigned short* __restrict__ aout,
                                               float* __restrict__ fout,
                                               float* __restrict__ snext,
                                               int n) {
    constexpr int HK = 4 * K;
    constexpr int KS = HK / 32;       // MFMA k-steps
    constexpr int NC = D / 16;        // output 16-col chunks
    constexpr int CW = NC / 4;        // chunks per wave
    constexpr int ROWB = HK + 8;      // padded LDS row (bf16 units)
    constexpr int DW = K / 32;        // uints per lane in gather (2 or 4)

    __shared__ __bf16 gh[16 * ROWB];
    __shared__ __bf16 gl[16 * ROWB];
    __shared__ float4 A_lds[16];
    __shared__ float4 sc_lds[4][16];

    int t = threadIdx.x;
    int r0 = blockIdx.x * 16;
    int n4 = t >> 4, sl = t & 15;
    int node = r0 + n4;

    // ---- gather phase ----
    float acc[4][2 * DW];
#pragma unroll
    for (int h = 0; h < 4; ++h)
#pragma unroll
        for (int j = 0; j < 2 * DW; ++j) acc[h][j] = 0.f;
    float4 aA = make_float4(0.f, 0.f, 0.f, 0.f);

    auto accum = [&](float4 al, const unsigned* u) {
#pragma unroll
        for (int j = 0; j < DW; ++j) {
            float x0 = blo(u[j]), x1 = bhi(u[j]);
            acc[0][2 * j] += al.x * x0; acc[0][2 * j + 1] += al.x * x1;
            acc[1][2 * j] += al.y * x0; acc[1][2 * j + 1] += al.y * x1;
            acc[2][2 * j] += al.z * x0; acc[2][2 * j + 1] += al.z * x1;
            acc[3][2 * j] += al.w * x0; acc[3][2 * j + 1] += al.w * x1;
        }
        aA.x += al.x; aA.y += al.y; aA.z += al.z; aA.w += al.w;
    };

    if (node < n) {
        int beg = rowptr[node], end = rowptr[node + 1];
        int e = beg;
        for (; e + 1 < end; e += 2) {
            int snA = srcs[e], snB = srcs[e + 1];
            float4 alA = *(const float4*)&alpha[(size_t)e * 4];
            float4 alB = *(const float4*)&alpha[(size_t)(e + 1) * 4];
            unsigned uA[DW], uB[DW];
            if constexpr (DW == 4) {
                uint4 ta = ((const uint4*)xb)[(size_t)snA * 16 + sl];
                uint4 tb = ((const uint4*)xb)[(size_t)snB * 16 + sl];
                uA[0] = ta.x; uA[1] = ta.y; uA[2] = ta.z; uA[3] = ta.w;
                uB[0] = tb.x; uB[1] = tb.y; uB[2] = tb.z; uB[3] = tb.w;
            } else {
                uint2 ta = ((const uint2*)xb)[(size_t)snA * 16 + sl];
                uint2 tb = ((const uint2*)xb)[(size_t)snB * 16 + sl];
                uA[0] = ta.x; uA[1] = ta.y;
                uB[0] = tb.x; uB[1] = tb.y;
            }
            accum(alA, uA);
            accum(alB, uB);
        }
        if (e < end) {
            int sn = srcs[e];
            float4 al = *(const float4*)&alpha[(size_t)e * 4];
            unsigned u[DW];
            if constexpr (DW == 4) {
                uint4 ta = ((const uint4*)xb)[(size_t)sn * 16 + sl];
                u[0] = ta.x; u[1] = ta.y; u[2] = ta.z; u[3] = ta.w;
            } else {
                uint2 ta = ((const uint2*)xb)[(size_t)sn * 16 + sl];
                u[0] = ta.x; u[1] = ta.y;
            }
            accum(al, u);
        }
    }

    // ---- split hi/lo into LDS ----
    {
        size_t gbase = (size_t)n4 * ROWB;
#pragma unroll
        for (int h = 0; h < 4; ++h) {
            if constexpr (DW == 4) {
                bf16x8 vh, vl;
#pragma unroll
                for (int j = 0; j < 8; ++j) {
                    __bf16 hi = (__bf16)acc[h][j];
                    vh[j] = hi;
                    vl[j] = (__bf16)(acc[h][j] - (float)hi);
                }
                *(bf16x8*)&gh[gbase + h * K + sl * 8] = vh;
                *(bf16x8*)&gl[gbase + h * K + sl * 8] = vl;
            } else {
                bf16x4 vh, vl;
#pragma unroll
                for (int j = 0; j < 4; ++j) {
                    __bf16 hi = (__bf16)acc[h][j];
                    vh[j] = hi;
                    vl[j] = (__bf16)(acc[h][j] - (float)hi);
                }
                *(bf16x4*)&gh[gbase + h * K + sl * 4] = vh;
                *(bf16x4*)&gl[gbase + h * K + sl * 4] = vl;
            }
        }
        if (sl == 0) A_lds[n4] = aA;
    }
    __syncthreads();

    // ---- MFMA phase: D-split across waves ----
    int wid = t >> 6, lane = t & 63;
    int lrow = lane & 15, gq = lane >> 4;

    f32x4 acc2[CW];
#pragma unroll
    for (int cw = 0; cw < CW; ++cw)
#pragma unroll
        for (int r = 0; r < 4; ++r) acc2[cw][r] = 0.f;

    const __bf16* wsp = (const __bf16*)Ws;
#pragma unroll
    for (int ks = 0; ks < KS; ++ks) {
        bf16x8 fh = *(const bf16x8*)&gh[(size_t)lrow * ROWB + ks * 32 + gq * 8];
        bf16x8 fl = *(const bf16x8*)&gl[(size_t)lrow * ROWB + ks * 32 + gq * 8];
#pragma unroll
        for (int cw = 0; cw < CW; ++cw) {
            int c = wid * CW + cw;
            bf16x8 bfr = *(const bf16x8*)(wsp + (size_t)(c * 16 + lrow) * HK + ks * 32 + gq * 8);
            acc2[cw] = __builtin_amdgcn_mfma_f32_16x16x32_bf16(fh, bfr, acc2[cw], 0, 0, 0);
            acc2[cw] = __builtin_amdgcn_mfma_f32_16x16x32_bf16(fl, bfr, acc2[cw], 0, 0, 0);
        }
    }

    // ---- epilogue ----
    float4 Ar[4];
#pragma unroll
    for (int r = 0; r < 4; ++r) Ar[r] = A_lds[gq * 4 + r];

    float sc[4][4];
#pragma unroll
    for (int h = 0; h < 4; ++h)
#pragma unroll
        for (int r = 0; r < 4; ++r) sc[h][r] = 0.f;

#pragma unroll
    for (int cw = 0; cw < CW; ++cw) {
        int col = (wid * CW + cw) * 16 + lrow;
        float bb0 = bias[0 * D + col], bb1 = bias[1 * D + col];
        float bb2 = bias[2 * D + col], bb3 = bias[3 * D + col];
        float vv0 = 0.f, vv1 = 0.f, vv2 = 0.f, vv3 = 0.f;
        if constexpr (!LAST) {
            vv0 = vnext[0 * D + col]; vv1 = vnext[1 * D + col];
            vv2 = vnext[2 * D + col]; vv3 = vnext[3 * D + col];
        }
#pragma unroll
        for (int r = 0; r < 4; ++r) {
            float val = acc2[cw][r] + Ar[r].x * bb0 + Ar[r].y * bb1 + Ar[r].z * bb2 + Ar[r].w * bb3;
            int row = r0 + gq * 4 + r;
            if constexpr (LAST) {
                if (row < n) fout[(size_t)row * D + col] = val;
            } else {
                val = fmaxf(val, 0.f);
                if (row < n) aout[(size_t)row * D + col] = fbits(val);
                sc[0][r] += val * vv0;
                sc[1][r] += val * vv1;
                sc[2][r] += val * vv2;
                sc[3][r] += val * vv3;
            }
        }
    }

    if constexpr (!LAST) {
#pragma unroll
        for (int m = 1; m < 16; m <<= 1) {
#pragma unroll
            for (int h = 0; h < 4; ++h)
#pragma unroll
                for (int r = 0; r < 4; ++r) sc[h][r] += __shfl_xor(sc[h][r], m, 64);
        }
        if (lrow < 4) {
            int r = lrow;
            sc_lds[wid][gq * 4 + r] = make_float4(sc[0][r], sc[1][r], sc[2][r], sc[3][r]);
        }
        __syncthreads();
        if (t < 16) {
            int row = r0 + t;
            if (row < n) {
                float4 s0 = sc_lds[0][t], s1 = sc_lds[1][t];
                float4 s2 = sc_lds[2][t], s3 = sc_lds[3][t];
                *(float4*)&snext[(size_t)row * 4] =
                    make_float4(s0.x + s1.x + s2.x + s3.x + cnext[0],
                                s0.y + s1.y + s2.y + s3.y + cnext[1],
                                s0.z + s1.z + s2.z + s3.z + cnext[2],
                                s0.w + s1.w + s2.w + s3.w + cnext[3]);
            }
        }
    }
}

// ---------------- launch ----------------

extern "C" void kernel_launch(void* const* d_in, const int* in_sizes, int n_in,
                              void* d_out, int out_size, void* d_ws, size_t ws_size,
                              hipStream_t stream) {
    const float* x    = (const float*)d_in[0];
    const int*   ei   = (const int*)d_in[1];
    const float* ew   = (const float*)d_in[2];
    const float* W1   = (const float*)d_in[3];
    const float* b1   = (const float*)d_in[4];
    const float* att1 = (const float*)d_in[5];
    const float* W2   = (const float*)d_in[6];
    const float* b2   = (const float*)d_in[7];
    const float* att2 = (const float*)d_in[8];
    const float* W3   = (const float*)d_in[9];
    const float* b3   = (const float*)d_in[10];
    const float* att3 = (const float*)d_in[11];

    const int N = in_sizes[0] / 128;
    const int E = in_sizes[2];
    const int* src = ei;
    const int* dst = ei + E;

    char* wp = (char*)d_ws;
    auto alloc = [&](size_t bytes) -> void* {
        void* p = (void*)wp;
        wp += (bytes + 511) & ~(size_t)511;
        return p;
    };
    int*   deg    = (int*)alloc((size_t)N * 4);
    int*   rowptr = (int*)alloc((size_t)(N + 1) * 4);
    int*   fill   = (int*)alloc((size_t)N * 4);
    int*   bsum   = (int*)alloc(256 * 4);
    int*   boff   = (int*)alloc(256 * 4);
    int*   srcs   = (int*)alloc((size_t)E * 4);
    float* wsrt   = (float*)alloc((size_t)E * 4);
    unsigned* xb  = (unsigned*)alloc((size_t)N * 64 * 4);     // x bf16 [N,128]
    float* s      = (float*)alloc((size_t)N * 4 * 4);
    float* alpha  = (float*)alloc((size_t)E * 4 * 4);
    unsigned short* a1 = (unsigned short*)alloc((size_t)N * 64 * 2);
    unsigned short* a2 = (unsigned short*)alloc((size_t)N * 64 * 2);
    float* v1 = (float*)alloc(512 * 4);
    float* v2 = (float*)alloc(256 * 4);
    float* v3 = (float*)alloc(256 * 4);
    float* c1 = (float*)alloc(16);
    float* c2 = (float*)alloc(16);
    float* c3 = (float*)alloc(16);
    unsigned short* Ws1 = (unsigned short*)alloc(32768 * 2);
    unsigned short* Ws2 = (unsigned short*)alloc(16384 * 2);
    unsigned short* Ws3 = (unsigned short*)alloc(32768 * 2);

    // --- prep (independent of CSR) ---
    wpack3_k<<<320, 256, 0, stream>>>(W1, W2, W3, Ws1, Ws2, Ws3);
    prep_k<<<5, 256, 0, stream>>>(W1, att1, b1, W2, att2, b2, W3, att3, b3,
                                  v1, v2, v3, c1, c2, c3);
    int gx = (N * 64 + 255) / 256;
    xpack_score_k<<<gx, 256, 0, stream>>>(x, v1, c1, xb, s, N);

    // --- CSR build (shared by all 3 layers) ---
    hipMemsetAsync(deg, 0, (size_t)N * 4, stream);
    int ge = (E + 255) / 256;
    int nb = (N + 2047) / 2048;
    hist_k<<<ge, 256, 0, stream>>>(dst, deg, E);
    partial_k<<<nb, 256, 0, stream>>>(deg, bsum, N);
    bscan_k<<<1, 256, 0, stream>>>(bsum, boff, nb);
    rescan_k<<<nb, 256, 0, stream>>>(deg, boff, rowptr, fill, N, E);
    scatter_k<<<ge, 256, 0, stream>>>(src, dst, ew, fill, srcs, wsrt, E);

    int gf = (N + 15) / 16;  // fused: 16 nodes per block

    // --- layer 1: gather x (K=128) -> [N,512]@[512,64] ---
    alpha_k<<<ge, 256, 0, stream>>>(srcs, wsrt, s, alpha, E);
    fused_k<128, 64, false><<<gf, 256, 0, stream>>>(rowptr, srcs, alpha, xb, Ws1, b1,
                                                    v2, c2, a1, nullptr, s, N);

    // --- layer 2: gather a1 (K=64) -> [N,256]@[256,64] ---
    alpha_k<<<ge, 256, 0, stream>>>(srcs, wsrt, s, alpha, E);
    fused_k<64, 64, false><<<gf, 256, 0, stream>>>(rowptr, srcs, alpha, (const unsigned*)a1,
                                                   Ws2, b2, v3, c3, a2, nullptr, s, N);

    // --- layer 3: gather a2 (K=64) -> [N,256]@[256,128] ---
    alpha_k<<<ge, 256, 0, stream>>>(srcs, wsrt, s, alpha, E);
    fused_k<64, 128, true><<<gf, 256, 0, stream>>>(rowptr, srcs, alpha, (const unsigned*)a2,
                                                   Ws3, b3, nullptr, nullptr, nullptr,
                                                   (float*)d_out, nullptr, N);
}